// Round 4
// baseline (277.349 us; speedup 1.0000x reference)
//
#include <hip/hip_runtime.h>
#include <math.h>

// Problem shape (fixed by reference setup_inputs):
//   B=32, H=64, W=64, C=256, NHWC layout (C contiguous).
//   Outputs: x (B,H,W,C) fp32 then gate (B,1,1,C) fp32, concatenated flat.
#define B_ 32
#define HW_ 4096          // 64*64
#define C_ 256
#define C4_ 64            // C/4
#define NCHUNK 64         // spatial chunks per batch in pass 1
#define CHUNK 64          // HW_/NCHUNK positions per chunk

// Native vector type — required for __builtin_nontemporal_store (HIP's
// float4 is a class and is rejected by the builtin).
typedef float vfloat4 __attribute__((ext_vector_type(4)));

// ---------------- Kernel 1: partial spatial sum/max reduction ----------------
// Grid: B*NCHUNK = 2048 blocks (8 blocks/CU -> full occupancy), 256 threads.
// Thread layout: t = pg*64 + c4, pg in [0,4) position-group, c4 in [0,64)
// float4 channel group. Each thread strides positions by 4 (16 loads, fully
// unrolled), float4 over channels (16B/lane, wave reads 1KiB contiguous).
__global__ __launch_bounds__(256) void pool_partial_kernel(
    const float* __restrict__ in, float* __restrict__ ws_sum,
    float* __restrict__ ws_max) {
  const int b = blockIdx.x >> 6;   // / NCHUNK
  const int k = blockIdx.x & 63;   // % NCHUNK
  const int t = threadIdx.x;
  const int c4 = t & 63;
  const int pg = t >> 6;           // 0..3

  const float4* in4 = (const float4*)in;
  // float4 index of (b, pos = k*CHUNK + pg, channel-group c4)
  long base = (long)b * (HW_ * C4_) + (long)(k * CHUNK + pg) * C4_ + c4;

  float4 s = make_float4(0.f, 0.f, 0.f, 0.f);
  float4 m = make_float4(-INFINITY, -INFINITY, -INFINITY, -INFINITY);
#pragma unroll
  for (int p = 0; p < CHUNK; p += 4) {
    float4 v = in4[base + (long)p * C4_];
    s.x += v.x; s.y += v.y; s.z += v.z; s.w += v.w;
    m.x = fmaxf(m.x, v.x); m.y = fmaxf(m.y, v.y);
    m.z = fmaxf(m.z, v.z); m.w = fmaxf(m.w, v.w);
  }

  __shared__ float4 ssum[256];
  __shared__ float4 smax[256];
  ssum[t] = s;
  smax[t] = m;
  __syncthreads();

  if (pg == 0) {
#pragma unroll
    for (int q = 1; q < 4; ++q) {
      float4 s2 = ssum[q * 64 + c4];
      float4 m2 = smax[q * 64 + c4];
      s.x += s2.x; s.y += s2.y; s.z += s2.z; s.w += s2.w;
      m.x = fmaxf(m.x, m2.x); m.y = fmaxf(m.y, m2.y);
      m.z = fmaxf(m.z, m2.z); m.w = fmaxf(m.w, m2.w);
    }
    float4* wsum4 = (float4*)ws_sum;
    float4* wmax4 = (float4*)ws_max;
    wsum4[(b * NCHUNK + k) * C4_ + c4] = s;
    wmax4[(b * NCHUNK + k) * C4_ + c4] = m;
  }
}

// ---------------- Kernel 2: finish reduction + GEMM + BN + gate ----------------
// Grid: B blocks, 256 threads (one per channel). Writes gate directly to the
// d_out tail; kernel 3 reads it from there (same stream, ordered).
__global__ __launch_bounds__(256) void gate_kernel(
    const float* __restrict__ ws_sum, const float* __restrict__ ws_max,
    const float* __restrict__ factor, const float* __restrict__ W1,
    const float* __restrict__ b1, const float* __restrict__ gamma,
    const float* __restrict__ beta, const float* __restrict__ bn_mean,
    const float* __restrict__ bn_var, const float* __restrict__ Wg,
    const float* __restrict__ bg, const float* __restrict__ gumbel,
    float* __restrict__ out_gate) {
  const int b = blockIdx.x;
  const int j = threadIdx.x;  // channel

  float s = 0.f;
  float m = -INFINITY;
#pragma unroll 8
  for (int k = 0; k < NCHUNK; ++k) {
    s += ws_sum[(b * NCHUNK + k) * C_ + j];
    m = fmaxf(m, ws_max[(b * NCHUNK + k) * C_ + j]);
  }

  // softmax over the 2 blend factors
  float a0 = factor[0], a1 = factor[1];
  float mx = fmaxf(a0, a1);
  float e0 = expf(a0 - mx), e1 = expf(a1 - mx);
  float inv = 1.f / (e0 + e1);
  float f0 = e0 * inv, f1 = e1 * inv;

  __shared__ float pool[C_];
  pool[j] = (s * (1.0f / (float)HW_)) * f0 + m * f1;
  __syncthreads();

  // h[j] = sum_c pool[c] * W1[c,j] + b1[j]; 4 independent FMA chains for ILP
  float h0 = 0.f, h1 = 0.f, h2 = 0.f, h3 = 0.f;
#pragma unroll 8
  for (int c = 0; c < C_; c += 4) {
    h0 = fmaf(pool[c + 0], W1[(c + 0) * C_ + j], h0);
    h1 = fmaf(pool[c + 1], W1[(c + 1) * C_ + j], h1);
    h2 = fmaf(pool[c + 2], W1[(c + 2) * C_ + j], h2);
    h3 = fmaf(pool[c + 3], W1[(c + 3) * C_ + j], h3);
  }
  float h = ((h0 + h1) + (h2 + h3)) + b1[j];
  // BatchNorm (inference) + ReLU
  h = gamma[j] * (h - bn_mean[j]) * rsqrtf(bn_var[j] + 1e-3f) + beta[j];
  h = fmaxf(h, 0.f);

  // grouped 1x1 conv -> 2 logits, + gumbel; hard sample = argmax
  float z0 = fmaf(h, Wg[j * 2 + 0], bg[j * 2 + 0]) + gumbel[(b * C_ + j) * 2 + 0];
  float z1 = fmaf(h, Wg[j * 2 + 1], bg[j * 2 + 1]) + gumbel[(b * C_ + j) * 2 + 1];
  // argmax picks index 0 on ties -> gate = 1 iff z1 > z0 strictly
  float g = (z1 > z0) ? 1.0f : 0.0f;

  out_gate[b * C_ + j] = g;
}

// ---------------- Kernel 3: x = inputs * gate[b,c] ----------------
// 4096 blocks x 256 threads; each thread handles 8 float4s at the same
// channel-group (one gate load reused 8x), 8 independent load->mul->store
// chains for memory-level parallelism. Nontemporal stores keep the
// L3-resident input from being evicted by the output stream.
__global__ __launch_bounds__(256) void apply_gate_kernel(
    const float* __restrict__ in, const float* __restrict__ gate,
    float* __restrict__ out) {
  const vfloat4* in4 = (const vfloat4*)in;
  const vfloat4* g4 = (const vfloat4*)gate;
  vfloat4* out4 = (vfloat4*)out;

  const int t = threadIdx.x;
  const int lane = t & 63;   // channel-group c4
  const int grp = t >> 6;    // 0..3

  // Block covers 2048 consecutive float4s = 32 positions x 64 channel-groups.
  long base = (long)blockIdx.x * 2048;
  long i0 = base + (long)grp * 512 + lane;  // thread's 8 f4s at +j*64, j=0..7

  int b = (int)(base >> 18);  // 2^18 float4s per batch; constant per block
  vfloat4 g = g4[b * C4_ + lane];

  vfloat4 v[8];
#pragma unroll
  for (int j = 0; j < 8; ++j) v[j] = in4[i0 + (long)j * 64];
#pragma unroll
  for (int j = 0; j < 8; ++j) v[j] *= g;
#pragma unroll
  for (int j = 0; j < 8; ++j)
    __builtin_nontemporal_store(v[j], &out4[i0 + (long)j * 64]);
}

extern "C" void kernel_launch(void* const* d_in, const int* in_sizes, int n_in,
                              void* d_out, int out_size, void* d_ws, size_t ws_size,
                              hipStream_t stream) {
  const float* inputs  = (const float*)d_in[0];
  const float* factor  = (const float*)d_in[1];
  const float* W1      = (const float*)d_in[2];
  const float* b1      = (const float*)d_in[3];
  const float* gamma   = (const float*)d_in[4];
  const float* beta    = (const float*)d_in[5];
  const float* bn_mean = (const float*)d_in[6];
  const float* bn_var  = (const float*)d_in[7];
  const float* Wg      = (const float*)d_in[8];
  const float* bg      = (const float*)d_in[9];
  const float* gumbel  = (const float*)d_in[10];

  float* out_x = (float*)d_out;                          // B*H*W*C floats
  float* out_gate = (float*)d_out + (long)B_ * HW_ * C_; // B*C floats

  // Workspace layout (floats):
  float* ws_sum  = (float*)d_ws;                   // B*NCHUNK*C = 524288
  float* ws_max  = ws_sum + B_ * NCHUNK * C_;      // 524288

  pool_partial_kernel<<<B_ * NCHUNK, 256, 0, stream>>>(inputs, ws_sum, ws_max);

  gate_kernel<<<B_, 256, 0, stream>>>(ws_sum, ws_max, factor, W1, b1, gamma,
                                      beta, bn_mean, bn_var, Wg, bg, gumbel,
                                      out_gate);

  const long n4 = (long)B_ * HW_ * C4_;  // 2^23 float4s
  apply_gate_kernel<<<(int)(n4 / 2048), 256, 0, stream>>>(inputs, out_gate, out_x);
}